// Round 9
// baseline (315.442 us; speedup 1.0000x reference)
//
#include <hip/hip_runtime.h>

// MNIST_RNN R16: 512 waves, 4-stream ring. R15 post-mortem: stagger won
// at dispatch level exactly as predicted (206->117us, VALUBusy 22.7->
// 39.8) but GRADED didn't move (233->236). All 7 graded/rocprof pairs:
// graded = f(wave count) only: 2048w->260-268, 1024w->233/236 (with
// dispatches 206 AND 117 -> identical graded!). Model: graded ~ 200us
// masked overhead + ~30ns/wave; dispatch below the mask is invisible.
// Probe+win: 64 samples/wave -> 512 waves. To keep dispatch under the
// mask (2x117=234 would surface), deepen the stagger to a 4-stream
// RING: iteration = 4 phases, phase k = {CMP(k) | RDA(k+1) | WRH(k-1)},
// so every phase overlaps one stream's trans/VALU/MFMA compute with two
// streams' DS. x-prefetch depth-1 (issue P0, consume P2, ~2us slack)
// saves 28 VGPR. launch_bounds(64,1): full VGPR file at 1 wave/SIMD.
// Decision: graded ~215-225 -> wave model confirmed (256-wave next);
// ~234 -> floor, stop; >245 -> dispatch surfaced, check rocprof; VGPR
// 512+scratch -> spill, back off to 3 streams.
// Numerics identical per sample to R12-R15.

#define HDIM 10
#define DDIM 28
#define TSTEPS 28
#define NX 28          // x elements per lane (64*28/64)

typedef __attribute__((ext_vector_type(8))) short short8;
typedef __attribute__((ext_vector_type(4))) float f32x4;

__device__ __forceinline__ unsigned short bf16_rne(float f) {
    unsigned u = __builtin_bit_cast(unsigned, f);
    u += 0x7FFFu + ((u >> 16) & 1u);
    return (unsigned short)(u >> 16);
}
__device__ __forceinline__ float bf16_f(unsigned short h) {
    unsigned u = ((unsigned)h) << 16;
    return __builtin_bit_cast(float, u);
}
// packed {lo:hi} bf16 split of v: low16 = bf16_rne(v), high16 = bf16_rne(v - hi)
__device__ __forceinline__ unsigned pk_hl(float v) {
    unsigned a, p;
    const float z = 0.0f;
    asm("v_cvt_pk_bf16_f32 %0, %1, %2" : "=v"(a) : "v"(v), "v"(z));
    const float hif = __builtin_bit_cast(float, a << 16);
    const float d = v - hif;
    asm("v_cvt_pk_bf16_f32 %0, %1, %2" : "=v"(p) : "v"(v), "v"(d));
    return p;
}
__device__ __forceinline__ float sig_f(float v) {
    return __builtin_amdgcn_rcpf(1.0f + __expf(-v));
}
__device__ __forceinline__ float tanh_f(float v) {
    return 2.0f * __builtin_amdgcn_rcpf(1.0f + __expf(-2.0f * v)) - 1.0f;
}

#define FENCE() __asm volatile("" ::: "memory")
#define WR32(arrp, sidx, val) (*(unsigned*)&(arrp)[(sidx)] = (val))

// ---- per-stream building blocks (MH = 0..3, compile-time literal) ----

// read A-fragments for stream MH (rows 16*MH + lm)
#define RDA(MH) do {                                                          \
    _Pragma("unroll")                                                         \
    for (int c = 0; c < 2; ++c)                                               \
        A1f[MH][c] = *(const short8*)&uA1w[(16 * (MH) + lm) * 72 + 32 * c + 8 * q]; \
    _Pragma("unroll")                                                         \
    for (int c = 0; c < 4; ++c)                                               \
        A0f[MH][c] = *(const short8*)&uA0w[(16 * (MH) + lm) * 136 + 32 * c + 8 * q]; \
} while (0)

// MFMA + act + cell update for stream MH -> h0v[MH], h1v[MH]
#define CMP(MH) do {                                                          \
    f32x4 C_[4], D_[4];                                                       \
    _Pragma("unroll")                                                         \
    for (int T4 = 0; T4 < 4; ++T4) {                                          \
        f32x4 accD = {bias1[T4], bias1[T4], bias1[T4], bias1[T4]};            \
        _Pragma("unroll")                                                     \
        for (int c = 0; c < 2; ++c)                                           \
            accD = __builtin_amdgcn_mfma_f32_16x16x32_bf16(A1f[MH][c], B1[T4][c], accD, 0, 0, 0); \
        D_[T4] = accD;                                                        \
        f32x4 accC = {bias0[T4], bias0[T4], bias0[T4], bias0[T4]};            \
        _Pragma("unroll")                                                     \
        for (int c = 0; c < 4; ++c)                                           \
            accC = __builtin_amdgcn_mfma_f32_16x16x32_bf16(A0f[MH][c], B0[T4][c], accC, 0, 0, 0); \
        C_[T4] = accC;                                                        \
    }                                                                         \
    _Pragma("unroll")                                                         \
    for (int r = 0; r < 4; ++r) {                                             \
        const float i1 = sig_f(D_[0][r]);                                     \
        const float f1 = sig_f(D_[1][r]);                                     \
        const float g1 = tanh_f(D_[2][r]);                                    \
        const float o1 = sig_f(D_[3][r]);                                     \
        const float c1 = f1 * c1s[MH][r] + i1 * g1;                           \
        c1s[MH][r] = c1;                                                      \
        h1v[MH][r] = o1 * tanh_f(c1);                                         \
        const float i0 = sig_f(C_[0][r]);                                     \
        const float f0 = sig_f(C_[1][r]);                                     \
        const float g0 = tanh_f(C_[2][r]);                                    \
        const float o0 = sig_f(C_[3][r]);                                     \
        const float c0 = f0 * c0s[MH][r] + i0 * g0;                           \
        c0s[MH][r] = c0;                                                      \
        h0v[MH][r] = o0 * tanh_f(c0);                                         \
    }                                                                         \
} while (0)

// write h1(t), h0(t+1) of stream MH back to the A-panels
#define WRH(MH) do {                                                          \
    if (lm < 10) {                                                            \
        _Pragma("unroll")                                                     \
        for (int r = 0; r < 4; ++r) {                                         \
            const int m = 16 * (MH) + 4 * q + r;                              \
            const unsigned p1 = pk_hl(h1v[MH][r]);                            \
            unsigned short* r1 = &uA1w[m * 72];                               \
            WR32(r1, 20 + 2 * lm, p1); r1[50 + lm] = (unsigned short)p1;      \
            const unsigned p0 = pk_hl(h0v[MH][r]);                            \
            WR32(r1, 2 * lm, p0);      r1[40 + lm] = (unsigned short)p0;      \
            unsigned short* r0 = &uA0w[m * 136];                              \
            WR32(r0, 56 + 2 * lm, p0); r0[104 + lm] = (unsigned short)p0;     \
        }                                                                     \
    }                                                                         \
} while (0)

#define XLOAD() do {                                                          \
    _Pragma("unroll")                                                         \
    for (int i = 0; i < NX; ++i) { xoff[i] += DDIM; xN[i] = x[xoff[i]]; }     \
} while (0)

#define XWRITE() do {                                                         \
    _Pragma("unroll")                                                         \
    for (int i = 0; i < NX; ++i) {                                            \
        const unsigned p = pk_hl(xN[i]);                                      \
        WR32(uA0w, lofsA[i], p);                                              \
        uA0w[lofsB[i]] = (unsigned short)p;                                   \
    }                                                                         \
} while (0)

// one ring iteration: computes cell1(T)+cell0(T+1) for all 4 streams.
// Phase k: CMP(k) | RDA(k+1) | WRH(k-1). Stream k's WRH(T) lands in
// phase k+1 (stream 3's in next iteration's P0). x: issue at P0
// (x(T+2)), LDS-write at P2 (after RDA(3)'s reads of x(T+1); in-order
// DS pipe + may-alias program order preserve RAW/WAR).
#define RING(T, FIRST) do {                                                   \
    /* P0: WRH(3)@T-1 | RDA(1)@T | x(T+2) issue | CMP(0)@T */                 \
    if (!(FIRST)) { WRH(3); }                                                 \
    RDA(1);                                                                   \
    if ((T) < TSTEPS - 2) { XLOAD(); }                                        \
    CMP(0);                                                                   \
    FENCE();                                                                  \
    /* P1: WRH(0)@T | RDA(2)@T | CMP(1)@T */                                  \
    WRH(0);                                                                   \
    RDA(2);                                                                   \
    CMP(1);                                                                   \
    FENCE();                                                                  \
    /* P2: RDA(3)@T (before x-writes!) | WRH(1)@T | x(T+2) writes | CMP(2) */ \
    RDA(3);                                                                   \
    WRH(1);                                                                   \
    if ((T) < TSTEPS - 2) { XWRITE(); }                                       \
    CMP(2);                                                                   \
    FENCE();                                                                  \
    /* P3: WRH(2)@T | RDA(0)@T+1 | CMP(3)@T */                                \
    WRH(2);                                                                   \
    RDA(0);                                                                   \
    CMP(3);                                                                   \
    FENCE();                                                                  \
} while (0)

__global__ __launch_bounds__(64, 1) void lstm2_mfma_kernel(
    const float* __restrict__ x,
    const float* __restrict__ w_ih0, const float* __restrict__ w_hh0,
    const float* __restrict__ b_ih0, const float* __restrict__ b_hh0,
    const float* __restrict__ w_ih1, const float* __restrict__ w_hh1,
    const float* __restrict__ b_ih1, const float* __restrict__ b_hh1,
    const float* __restrict__ w_cls, const float* __restrict__ b_cls,
    float* __restrict__ out)
{
    // 1 wave per block, 64 samples (4 M-tiles of 16).
    // A0 row (stride 136 shorts): [ (x_d hi,lo) pairs d<28 : cols 0..55 |
    //   (h0_u hi,lo) pairs u<10 : 56..75 | x_d hi : 76..103 |
    //   h0_u hi : 104..113 | pad 114..135 ]   -- 64 rows
    // A1 row (stride 72): [ (h0 hi,lo) 0..19 | (h1 hi,lo) 20..39 |
    //   h0 hi 40..49 | h1 hi 50..59 | pad 60..71 ] -- 64 rows
    __shared__ __align__(16) unsigned short uA0w[64 * 136];
    __shared__ __align__(16) unsigned short uA1w[64 * 72];
    __shared__ __align__(16) float hfinw[64 * 12];

    const int l  = threadIdx.x;
    const int lm = l & 15;
    const int q  = l >> 4;
    const int sbase = blockIdx.x * 64;

    // ---- zero A-panel pads (NaN*0=NaN in MFMA) ----
    for (int i = l; i < 64 * 22; i += 64) uA0w[(i / 22) * 136 + 114 + (i % 22)] = 0;
    for (int i = l; i < 64 * 12; i += 64) uA1w[(i / 12) * 72 + 60 + (i % 12)] = 0;

    // ---- build B-fragments in registers (once; shared by all M-tiles) ----
    // 4 N-tiles: tile T row lm = gate g = 10T+lm (lm<10; rows lm>=10 zero).
    // T=0:i, T=1:f, T=2:g, T=3:o (torch gate order).
    // B0 k-zones: kk<76 pair zone -> w_hi (j2=kk>>1); [76,114) -> w_lo.
    // B1 k-zones: kk<40 pair zone -> w_hi; [40,60) -> w_lo.
    short8 B0[4][4], B1[4][2];
    const bool gvalid = (lm < 10);
    #pragma unroll
    for (int T = 0; T < 4; ++T) {
        const int g = 10 * T + lm;
        #pragma unroll
        for (int c = 0; c < 4; ++c) {
            #pragma unroll
            for (int j = 0; j < 8; ++j) {
                const int kk = 32 * c + 8 * q + j;
                unsigned short bits = 0;
                if (gvalid && kk < 114) {
                    if (kk < 76) {
                        const int j2 = kk >> 1;
                        const float w = (j2 < 28) ? w_ih0[g * 28 + j2]
                                                  : w_hh0[g * 10 + (j2 - 28)];
                        bits = bf16_rne(w);
                    } else {
                        const int d = kk - 76;
                        const float w = (d < 28) ? w_ih0[g * 28 + d]
                                                 : w_hh0[g * 10 + (d - 28)];
                        const unsigned short hi = bf16_rne(w);
                        bits = bf16_rne(w - bf16_f(hi));
                    }
                }
                B0[T][c][j] = (short)bits;
            }
        }
        #pragma unroll
        for (int c = 0; c < 2; ++c) {
            #pragma unroll
            for (int j = 0; j < 8; ++j) {
                const int kk = 32 * c + 8 * q + j;
                unsigned short bits = 0;
                if (gvalid && kk < 60) {
                    if (kk < 40) {
                        const int j2 = kk >> 1;
                        const float w = (j2 < 10) ? w_ih1[g * 10 + j2]
                                                  : w_hh1[g * 10 + (j2 - 10)];
                        bits = bf16_rne(w);
                    } else {
                        const int d = kk - 40;
                        const float w = (d < 10) ? w_ih1[g * 10 + d]
                                                 : w_hh1[g * 10 + (d - 10)];
                        const unsigned short hi = bf16_rne(w);
                        bits = bf16_rne(w - bf16_f(hi));
                    }
                }
                B1[T][c][j] = (short)bits;
            }
        }
    }

    // biases folded into MFMA C-init
    float bias0[4], bias1[4];
    #pragma unroll
    for (int T = 0; T < 4; ++T) {
        const int g = 10 * T + lm;
        bias0[T] = gvalid ? (b_ih0[g] + b_hh0[g]) : 0.0f;
        bias1[T] = gvalid ? (b_ih1[g] + b_hh1[g]) : 0.0f;
    }

    // ---- x pipeline: lane owns NX=28 of the wave's 1792 (sample,d) elems ----
    int xoff[NX], lofsA[NX], lofsB[NX];
    float xN[NX];
    #pragma unroll
    for (int i = 0; i < NX; ++i) {
        const int f = l + 64 * i;
        const int sm = f / 28, d = f - 28 * sm;
        lofsA[i] = sm * 136 + 2 * d;        // b32 (pair zone)
        lofsB[i] = sm * 136 + 76 + d;       // b16 (hi zone)
        xoff[i] = (sbase + sm) * (TSTEPS * DDIM) + d;
        xN[i] = x[xoff[i]];                 // t = 0
    }
    XWRITE();                               // x(0)
    // zero h zones (h0 = h1 = 0 at t=0)
    if (lm < 10) {
        #pragma unroll
        for (int mh = 0; mh < 4; ++mh) {
            #pragma unroll
            for (int r = 0; r < 4; ++r) {
                const int m = 16 * mh + 4 * q + r;
                unsigned short* r0 = &uA0w[m * 136];
                WR32(r0, 56 + 2 * lm, 0u); r0[104 + lm] = 0;
                unsigned short* r1 = &uA1w[m * 72];
                WR32(r1, 2 * lm, 0u);      r1[40 + lm] = 0;   // h0
                WR32(r1, 20 + 2 * lm, 0u); r1[50 + lm] = 0;   // h1
            }
        }
    }
    FENCE();

    float c0s[4][4] = {{0,0,0,0},{0,0,0,0},{0,0,0,0},{0,0,0,0}};
    float c1s[4][4] = {{0,0,0,0},{0,0,0,0},{0,0,0,0},{0,0,0,0}};
    float h1v[4][4] = {{0,0,0,0},{0,0,0,0},{0,0,0,0},{0,0,0,0}};
    float h0v[4][4];
    short8 A0f[4][4], A1f[4][2];

    // issue x(1) -> xN (consumed at end of prologue)
    XLOAD();

    // ================= prologue: cell0(0), all 4 streams =================
    #pragma unroll
    for (int mh = 0; mh < 4; ++mh)
        #pragma unroll
        for (int c = 0; c < 4; ++c)
            A0f[mh][c] = *(const short8*)&uA0w[(16 * mh + lm) * 136 + 32 * c + 8 * q];
    FENCE();
    #pragma unroll
    for (int mh = 0; mh < 4; ++mh) {
        f32x4 C_[4];
        #pragma unroll
        for (int T = 0; T < 4; ++T) {
            f32x4 acc = {bias0[T], bias0[T], bias0[T], bias0[T]};
            #pragma unroll
            for (int c = 0; c < 4; ++c)
                acc = __builtin_amdgcn_mfma_f32_16x16x32_bf16(A0f[mh][c], B0[T][c], acc, 0, 0, 0);
            C_[T] = acc;
        }
        #pragma unroll
        for (int r = 0; r < 4; ++r) {
            const float i0 = sig_f(C_[0][r]);
            const float f0 = sig_f(C_[1][r]);
            const float g0 = tanh_f(C_[2][r]);
            const float o0 = sig_f(C_[3][r]);
            const float c0 = f0 * c0s[mh][r] + i0 * g0;
            c0s[mh][r] = c0;
            h0v[mh][r] = o0 * tanh_f(c0);
        }
    }
    // write h0(1) zones (all streams) + x(1) zones
    if (lm < 10) {
        #pragma unroll
        for (int mh = 0; mh < 4; ++mh) {
            #pragma unroll
            for (int r = 0; r < 4; ++r) {
                const int m = 16 * mh + 4 * q + r;
                const unsigned p0 = pk_hl(h0v[mh][r]);
                unsigned short* r0 = &uA0w[m * 136];
                WR32(r0, 56 + 2 * lm, p0); r0[104 + lm] = (unsigned short)p0;
                unsigned short* r1 = &uA1w[m * 72];
                WR32(r1, 2 * lm, p0);      r1[40 + lm] = (unsigned short)p0;
            }
        }
    }
    XWRITE();                               // x(1) (loads long landed)
    FENCE();
    // ring warm-up: RDA(0)@0
    RDA(0);
    FENCE();

    // ===== main loop: ring iterations T=0..26 =====
    RING(0, 1);
    #pragma unroll 1
    for (int t = 1; t < TSTEPS - 1; ++t) {
        RING(t, 0);
    }
    // stream 3's deferred h-writes for T=26 (h1(26), h0(27))
    WRH(3);
    FENCE();

    // ================= epilogue: cell1(27), all streams =================
    #pragma unroll
    for (int mh = 0; mh < 4; ++mh)
        #pragma unroll
        for (int c = 0; c < 2; ++c)
            A1f[mh][c] = *(const short8*)&uA1w[(16 * mh + lm) * 72 + 32 * c + 8 * q];
    FENCE();
    #pragma unroll
    for (int mh = 0; mh < 4; ++mh) {
        f32x4 D_[4];
        #pragma unroll
        for (int T = 0; T < 4; ++T) {
            f32x4 acc = {bias1[T], bias1[T], bias1[T], bias1[T]};
            #pragma unroll
            for (int c = 0; c < 2; ++c)
                acc = __builtin_amdgcn_mfma_f32_16x16x32_bf16(A1f[mh][c], B1[T][c], acc, 0, 0, 0);
            D_[T] = acc;
        }
        #pragma unroll
        for (int r = 0; r < 4; ++r) {
            const float i1 = sig_f(D_[0][r]);
            const float f1 = sig_f(D_[1][r]);
            const float g1 = tanh_f(D_[2][r]);
            const float o1 = sig_f(D_[3][r]);
            const float c1 = f1 * c1s[mh][r] + i1 * g1;
            h1v[mh][r] = o1 * tanh_f(c1);
        }
    }

    // ---- classifier ----
    if (lm < 10) {
        #pragma unroll
        for (int mh = 0; mh < 4; ++mh)
            #pragma unroll
            for (int r = 0; r < 4; ++r)
                hfinw[(16 * mh + 4 * q + r) * 12 + lm] = h1v[mh][r];
    }
    FENCE();
    if (lm < 10) {
        float wc[10];
        #pragma unroll
        for (int j = 0; j < 10; ++j) wc[j] = w_cls[lm * 10 + j];
        const float bo = b_cls[lm];
        #pragma unroll
        for (int mh = 0; mh < 4; ++mh) {
            #pragma unroll
            for (int r = 0; r < 4; ++r) {
                const int m = 16 * mh + 4 * q + r;
                float acc = bo;
                #pragma unroll
                for (int j = 0; j < 10; ++j) acc += hfinw[m * 12 + j] * wc[j];
                out[(size_t)(sbase + m) * 10 + lm] = acc;
            }
        }
    }
}

extern "C" void kernel_launch(void* const* d_in, const int* in_sizes, int n_in,
                              void* d_out, int out_size, void* d_ws, size_t ws_size,
                              hipStream_t stream) {
    const float* x     = (const float*)d_in[0];
    const float* w_ih0 = (const float*)d_in[1];
    const float* w_hh0 = (const float*)d_in[2];
    const float* b_ih0 = (const float*)d_in[3];
    const float* b_hh0 = (const float*)d_in[4];
    const float* w_ih1 = (const float*)d_in[5];
    const float* w_hh1 = (const float*)d_in[6];
    const float* b_ih1 = (const float*)d_in[7];
    const float* b_hh1 = (const float*)d_in[8];
    const float* w_cls = (const float*)d_in[9];
    const float* b_cls = (const float*)d_in[10];
    float* out = (float*)d_out;

    const int B = in_sizes[0] / (TSTEPS * DDIM);   // 32768
    const int grid = B / 64;                       // 512 blocks x 1 wave x 64 samples

    hipLaunchKernelGGL(lstm2_mfma_kernel, dim3(grid), dim3(64), 0, stream,
                       x, w_ih0, w_hh0, b_ih0, b_hh0,
                       w_ih1, w_hh1, b_ih1, b_hh1,
                       w_cls, b_cls, out);
}

// Round 10
// 234.859 us; speedup vs baseline: 1.3431x; 1.3431x over previous
//
#include <hip/hip_runtime.h>

// MNIST_RNN R17: unified A-panel at the R15-winning config. R16 post-
// mortem: 4-stream ring spilled (VGPR_Count 244 vs ~400 live) -> 194us
// dispatch, graded 315; wave-count model dead. New model from all 8
// rounds: graded ~= dispatch + ~118us fixed overhead (diffs 115-121
// everywhere except R14's 27, whose rocprof 206 was profiling-perturbed
// — graded-implied ~115 matches R15). So: minimize dispatch; best real
// = R15's 117us. This round keeps R15 EXACTLY (2 streams, 32 samples/
// wave, 1024 waves, 3-region stagger, no spill) and cuts issued work:
// single panel, row = [x-pairs 56 | h0-pairs 20 | h1-pairs 20 | h0-hi
// 10 | h1-hi 10 | x-hi 28 | pad], stride 168. L0 reads base 0 (K=160,
// B0 zero over h1/pad zones); L1 reads base 56 (K=64, 16B-aligned, B1
// zero over trailing x-hi). h0 written ONCE: WRH 48->32 DS ops/BODY,
// one panel base, LDS 29.7->24.6KB. Cost: +8 MFMA (MfmaUtil 7.6%,
// free), +2 ds_read. Zero zones stay zeroed (NaN*0 guard). Numerics:
// K-sum order only (lsb).

#define HDIM 10
#define DDIM 28
#define TSTEPS 28
#define NX 14          // x elements per lane (32*28/64)
#define STR 168        // panel row stride (shorts); 16B-aligned, 2-way banks
// zone offsets within a row
#define ZH0P 56
#define ZH1P 76
#define ZH0H 96
#define ZH1H 106
#define ZXH  116
#define ZPAD 144

typedef __attribute__((ext_vector_type(8))) short short8;
typedef __attribute__((ext_vector_type(4))) float f32x4;

__device__ __forceinline__ unsigned short bf16_rne(float f) {
    unsigned u = __builtin_bit_cast(unsigned, f);
    u += 0x7FFFu + ((u >> 16) & 1u);
    return (unsigned short)(u >> 16);
}
__device__ __forceinline__ float bf16_f(unsigned short h) {
    unsigned u = ((unsigned)h) << 16;
    return __builtin_bit_cast(float, u);
}
// packed {lo:hi} bf16 split of v: low16 = bf16_rne(v), high16 = bf16_rne(v - hi)
__device__ __forceinline__ unsigned pk_hl(float v) {
    unsigned a, p;
    const float z = 0.0f;
    asm("v_cvt_pk_bf16_f32 %0, %1, %2" : "=v"(a) : "v"(v), "v"(z));
    const float hif = __builtin_bit_cast(float, a << 16);
    const float d = v - hif;
    asm("v_cvt_pk_bf16_f32 %0, %1, %2" : "=v"(p) : "v"(v), "v"(d));
    return p;
}
__device__ __forceinline__ float sig_f(float v) {
    return __builtin_amdgcn_rcpf(1.0f + __expf(-v));
}
__device__ __forceinline__ float tanh_f(float v) {
    return 2.0f * __builtin_amdgcn_rcpf(1.0f + __expf(-2.0f * v)) - 1.0f;
}

#define FENCE() __asm volatile("" ::: "memory")
#define WR32(arrp, sidx, val) (*(unsigned*)&(arrp)[(sidx)] = (val))

// ---- per-stream building blocks (MH = 0 or 1, compile-time) ----

// read A-fragments for stream MH (rows 16*MH + lm)
#define RDA(MH) do {                                                          \
    _Pragma("unroll")                                                         \
    for (int c = 0; c < 2; ++c)                                               \
        A1f[MH][c] = *(const short8*)&uAw[(16 * (MH) + lm) * STR + ZH0P + 32 * c + 8 * q]; \
    _Pragma("unroll")                                                         \
    for (int c = 0; c < 5; ++c)                                               \
        A0f[MH][c] = *(const short8*)&uAw[(16 * (MH) + lm) * STR + 32 * c + 8 * q]; \
} while (0)

// MFMA + act + cell update for stream MH -> h0v[MH], h1v[MH]
#define CMP(MH) do {                                                          \
    f32x4 C_[4], D_[4];                                                       \
    _Pragma("unroll")                                                         \
    for (int T4 = 0; T4 < 4; ++T4) {                                          \
        f32x4 accD = {bias1[T4], bias1[T4], bias1[T4], bias1[T4]};            \
        _Pragma("unroll")                                                     \
        for (int c = 0; c < 2; ++c)                                           \
            accD = __builtin_amdgcn_mfma_f32_16x16x32_bf16(A1f[MH][c], B1[T4][c], accD, 0, 0, 0); \
        D_[T4] = accD;                                                        \
        f32x4 accC = {bias0[T4], bias0[T4], bias0[T4], bias0[T4]};            \
        _Pragma("unroll")                                                     \
        for (int c = 0; c < 5; ++c)                                           \
            accC = __builtin_amdgcn_mfma_f32_16x16x32_bf16(A0f[MH][c], B0[T4][c], accC, 0, 0, 0); \
        C_[T4] = accC;                                                        \
    }                                                                         \
    _Pragma("unroll")                                                         \
    for (int r = 0; r < 4; ++r) {                                             \
        const float i1 = sig_f(D_[0][r]);                                     \
        const float f1 = sig_f(D_[1][r]);                                     \
        const float g1 = tanh_f(D_[2][r]);                                    \
        const float o1 = sig_f(D_[3][r]);                                     \
        const float c1 = f1 * c1s[MH][r] + i1 * g1;                           \
        c1s[MH][r] = c1;                                                      \
        h1v[MH][r] = o1 * tanh_f(c1);                                         \
        const float i0 = sig_f(C_[0][r]);                                     \
        const float f0 = sig_f(C_[1][r]);                                     \
        const float g0 = tanh_f(C_[2][r]);                                    \
        const float o0 = sig_f(C_[3][r]);                                     \
        const float c0 = f0 * c0s[MH][r] + i0 * g0;                           \
        c0s[MH][r] = c0;                                                      \
        h0v[MH][r] = o0 * tanh_f(c0);                                         \
    }                                                                         \
} while (0)

// write h1(t), h0(t+1) of stream MH back to the panel (single copy each)
#define WRH(MH) do {                                                          \
    if (lm < 10) {                                                            \
        _Pragma("unroll")                                                     \
        for (int r = 0; r < 4; ++r) {                                         \
            const int m = 16 * (MH) + 4 * q + r;                              \
            unsigned short* rw = &uAw[m * STR];                               \
            const unsigned p1 = pk_hl(h1v[MH][r]);                            \
            WR32(rw, ZH1P + 2 * lm, p1); rw[ZH1H + lm] = (unsigned short)p1;  \
            const unsigned p0 = pk_hl(h0v[MH][r]);                            \
            WR32(rw, ZH0P + 2 * lm, p0); rw[ZH0H + lm] = (unsigned short)p0;  \
        }                                                                     \
    }                                                                         \
} while (0)

// one macro-iteration (staggered): computes cell1(T)+cell0(T+1) for both
// streams; mh1's h-writes are deferred to R1 of the NEXT iteration.
// P holds x(T+2) (issued one iteration ago); Q receives the x(T+3) issue.
#define BODY(P, Q, T, FIRST) do {                                             \
    /* R1: mh0 reads(T) ; mh1 h-writes(T-1) */                                \
    RDA(0);                                                                   \
    if (!(FIRST)) { WRH(1); }                                                 \
    FENCE();                                                                  \
    /* R2: x(T+3) load issue ; mh0 compute(T) ; mh1 reads(T) */               \
    if ((T) < TSTEPS - 3) {                                                   \
        _Pragma("unroll")                                                     \
        for (int i = 0; i < NX; ++i) { xoff[i] += DDIM; Q[i] = x[xoff[i]]; }  \
    }                                                                         \
    CMP(0);                                                                   \
    RDA(1);                                                                   \
    FENCE();                                                                  \
    /* R3: mh0 h-writes(T) ; x(T+2) writes ; mh1 compute(T) */                \
    WRH(0);                                                                   \
    if ((T) < TSTEPS - 2) {                                                   \
        _Pragma("unroll")                                                     \
        for (int i = 0; i < NX; ++i) {                                        \
            const unsigned p = pk_hl(P[i]);                                   \
            WR32(uAw, lofsA[i], p);                                           \
            uAw[lofsB[i]] = (unsigned short)p;                                \
        }                                                                     \
    }                                                                         \
    CMP(1);                                                                   \
    FENCE();                                                                  \
} while (0)

__global__ __launch_bounds__(128, 1) void lstm2_mfma_kernel(
    const float* __restrict__ x,
    const float* __restrict__ w_ih0, const float* __restrict__ w_hh0,
    const float* __restrict__ b_ih0, const float* __restrict__ b_hh0,
    const float* __restrict__ w_ih1, const float* __restrict__ w_hh1,
    const float* __restrict__ b_ih1, const float* __restrict__ b_hh1,
    const float* __restrict__ w_cls, const float* __restrict__ b_cls,
    float* __restrict__ out)
{
    // 2 independent waves per block; per-wave private LDS; no barriers.
    // Unified panel row (stride 168 shorts):
    //   [ (x_d hi,lo) pairs d<28 : 0..55 | (h0 hi,lo) pairs : 56..75 |
    //     (h1 hi,lo) pairs : 76..95 | h0 hi : 96..105 | h1 hi : 106..115 |
    //     x_d hi : 116..143 | pad(0) : 144..167 ]      -- 32 rows
    // L0 operand: base 0, K=160 (B0 zero over 76..95,106..115,144..159).
    // L1 operand: base 56, K=64  (B1 zero over kk>=60 -> 116..119).
    __shared__ __align__(16) unsigned short uAs[2][32 * STR];
    __shared__ __align__(16) float hfins[2][32 * 12];

    const int l   = threadIdx.x & 63;
    const int wid = threadIdx.x >> 6;
    const int lm  = l & 15;
    const int q   = l >> 4;
    const int sbase = (blockIdx.x * 2 + wid) * 32;

    unsigned short* const uAw = uAs[wid];
    float* const hfinw = hfins[wid];

    // ---- zero pad zone (NaN*0=NaN in MFMA; L0 reads through 159) ----
    for (int i = l; i < 32 * 24; i += 64) uAw[(i / 24) * STR + ZPAD + (i % 24)] = 0;

    // ---- build B-fragments in registers (once; shared by both M-tiles) ----
    // 4 N-tiles: tile T row lm = gate g = 10T+lm (lm<10; rows lm>=10 zero).
    // T=0:i, T=1:f, T=2:g, T=3:o (torch gate order).
    short8 B0[4][5], B1[4][2];
    const bool gvalid = (lm < 10);
    #pragma unroll
    for (int T = 0; T < 4; ++T) {
        const int g = 10 * T + lm;
        #pragma unroll
        for (int c = 0; c < 5; ++c) {
            #pragma unroll
            for (int j = 0; j < 8; ++j) {
                const int kk = 32 * c + 8 * q + j;
                unsigned short bits = 0;
                if (gvalid) {
                    if (kk < ZH0P) {                     // x pairs -> w_ih0 hi
                        bits = bf16_rne(w_ih0[g * 28 + (kk >> 1)]);
                    } else if (kk < ZH1P) {              // h0 pairs -> w_hh0 hi
                        bits = bf16_rne(w_hh0[g * 10 + ((kk - ZH0P) >> 1)]);
                    } else if (kk < ZH0H) {              // h1 pairs: not L0 input
                        bits = 0;
                    } else if (kk < ZH1H) {              // h0 hi -> w_hh0 lo
                        const float w = w_hh0[g * 10 + (kk - ZH0H)];
                        const unsigned short hi = bf16_rne(w);
                        bits = bf16_rne(w - bf16_f(hi));
                    } else if (kk < ZXH) {               // h1 hi: not L0 input
                        bits = 0;
                    } else if (kk < ZPAD) {              // x hi -> w_ih0 lo
                        const float w = w_ih0[g * 28 + (kk - ZXH)];
                        const unsigned short hi = bf16_rne(w);
                        bits = bf16_rne(w - bf16_f(hi));
                    }
                }
                B0[T][c][j] = (short)bits;
            }
        }
        #pragma unroll
        for (int c = 0; c < 2; ++c) {
            #pragma unroll
            for (int j = 0; j < 8; ++j) {
                const int kk = 32 * c + 8 * q + j;   // position ZH0P + kk
                unsigned short bits = 0;
                if (gvalid && kk < 60) {
                    if (kk < 20) {                       // h0 pairs -> w_ih1 hi
                        bits = bf16_rne(w_ih1[g * 10 + (kk >> 1)]);
                    } else if (kk < 40) {                // h1 pairs -> w_hh1 hi
                        bits = bf16_rne(w_hh1[g * 10 + ((kk - 20) >> 1)]);
                    } else if (kk < 50) {                // h0 hi -> w_ih1 lo
                        const float w = w_ih1[g * 10 + (kk - 40)];
                        const unsigned short hi = bf16_rne(w);
                        bits = bf16_rne(w - bf16_f(hi));
                    } else {                             // h1 hi -> w_hh1 lo
                        const float w = w_hh1[g * 10 + (kk - 50)];
                        const unsigned short hi = bf16_rne(w);
                        bits = bf16_rne(w - bf16_f(hi));
                    }
                }
                B1[T][c][j] = (short)bits;
            }
        }
    }

    // biases folded into MFMA C-init
    float bias0[4], bias1[4];
    #pragma unroll
    for (int T = 0; T < 4; ++T) {
        const int g = 10 * T + lm;
        bias0[T] = gvalid ? (b_ih0[g] + b_hh0[g]) : 0.0f;
        bias1[T] = gvalid ? (b_ih1[g] + b_hh1[g]) : 0.0f;
    }

    // ---- x pipeline: lane owns NX=14 of the wave's 896 (sample,d) elems ----
    int xoff[NX], lofsA[NX], lofsB[NX];
    float xA[NX], xB[NX];
    #pragma unroll
    for (int i = 0; i < NX; ++i) {
        const int f = l + 64 * i;
        const int sm = f / 28, d = f - 28 * sm;
        lofsA[i] = sm * STR + 2 * d;        // b32 (pair zone)
        lofsB[i] = sm * STR + ZXH + d;      // b16 (hi zone)
        xoff[i] = (sbase + sm) * (TSTEPS * DDIM) + d;
        xA[i] = x[xoff[i]];                 // t = 0
    }
    #pragma unroll
    for (int i = 0; i < NX; ++i) {
        const unsigned p = pk_hl(xA[i]);
        WR32(uAw, lofsA[i], p);
        uAw[lofsB[i]] = (unsigned short)p;
    }
    // zero h zones (h0 = h1 = 0 at t=0)
    if (lm < 10) {
        #pragma unroll
        for (int mh = 0; mh < 2; ++mh) {
            #pragma unroll
            for (int r = 0; r < 4; ++r) {
                unsigned short* rw = &uAw[(16 * mh + 4 * q + r) * STR];
                WR32(rw, ZH0P + 2 * lm, 0u); rw[ZH0H + lm] = 0;
                WR32(rw, ZH1P + 2 * lm, 0u); rw[ZH1H + lm] = 0;
            }
        }
    }
    FENCE();

    float c0s[2][4] = {{0,0,0,0},{0,0,0,0}}, c1s[2][4] = {{0,0,0,0},{0,0,0,0}};
    float h1v[2][4] = {{0,0,0,0},{0,0,0,0}};
    float h0v[2][4];
    short8 A0f[2][5], A1f[2][2];

    // issue x(1) -> xA (consumed at end of prologue)
    #pragma unroll
    for (int i = 0; i < NX; ++i) { xoff[i] += DDIM; xA[i] = x[xoff[i]]; }

    // ================= prologue: cell0(0), both streams =================
    #pragma unroll
    for (int mh = 0; mh < 2; ++mh)
        #pragma unroll
        for (int c = 0; c < 5; ++c)
            A0f[mh][c] = *(const short8*)&uAw[(16 * mh + lm) * STR + 32 * c + 8 * q];
    FENCE();
    // issue x(2) -> xB (consumed in main-loop body t=0)
    #pragma unroll
    for (int i = 0; i < NX; ++i) { xoff[i] += DDIM; xB[i] = x[xoff[i]]; }
    {
        f32x4 C[2][4];
        #pragma unroll
        for (int mh = 0; mh < 2; ++mh) {
            #pragma unroll
            for (int T = 0; T < 4; ++T) {
                f32x4 acc = {bias0[T], bias0[T], bias0[T], bias0[T]};
                #pragma unroll
                for (int c = 0; c < 5; ++c)
                    acc = __builtin_amdgcn_mfma_f32_16x16x32_bf16(A0f[mh][c], B0[T][c], acc, 0, 0, 0);
                C[mh][T] = acc;
            }
        }
        #pragma unroll
        for (int mh = 0; mh < 2; ++mh) {
            #pragma unroll
            for (int r = 0; r < 4; ++r) {
                const float i0 = sig_f(C[mh][0][r]);
                const float f0 = sig_f(C[mh][1][r]);
                const float g0 = tanh_f(C[mh][2][r]);
                const float o0 = sig_f(C[mh][3][r]);
                const float c0 = f0 * c0s[mh][r] + i0 * g0;
                c0s[mh][r] = c0;
                h0v[mh][r] = o0 * tanh_f(c0);
            }
        }
        if (lm < 10) {
            #pragma unroll
            for (int mh = 0; mh < 2; ++mh) {
                #pragma unroll
                for (int r = 0; r < 4; ++r) {
                    unsigned short* rw = &uAw[(16 * mh + 4 * q + r) * STR];
                    const unsigned p0 = pk_hl(h0v[mh][r]);
                    WR32(rw, ZH0P + 2 * lm, p0); rw[ZH0H + lm] = (unsigned short)p0;
                }
            }
        }
        // write x(1) (xA loads issued well before)
        #pragma unroll
        for (int i = 0; i < NX; ++i) {
            const unsigned p = pk_hl(xA[i]);
            WR32(uAw, lofsA[i], p);
            uAw[lofsB[i]] = (unsigned short)p;
        }
    }
    FENCE();

    // ===== main loop: staggered bodies; x buffers alternate roles =====
    BODY(xB, xA, 0, 1);
    BODY(xA, xB, 1, 0);
    #pragma unroll 1
    for (int tp = 1; tp < 13; ++tp) {
        BODY(xB, xA, 2 * tp, 0);
        BODY(xA, xB, 2 * tp + 1, 0);
    }
    BODY(xB, xA, 26, 0);

    // mh1's deferred h-writes for T=26 (h1(26), h0(27))
    WRH(1);
    FENCE();

    // ================= epilogue: cell1(27), both streams =================
    {
        #pragma unroll
        for (int mh = 0; mh < 2; ++mh)
            #pragma unroll
            for (int c = 0; c < 2; ++c)
                A1f[mh][c] = *(const short8*)&uAw[(16 * mh + lm) * STR + ZH0P + 32 * c + 8 * q];
        FENCE();
        f32x4 D[2][4];
        #pragma unroll
        for (int mh = 0; mh < 2; ++mh) {
            #pragma unroll
            for (int T = 0; T < 4; ++T) {
                f32x4 acc = {bias1[T], bias1[T], bias1[T], bias1[T]};
                #pragma unroll
                for (int c = 0; c < 2; ++c)
                    acc = __builtin_amdgcn_mfma_f32_16x16x32_bf16(A1f[mh][c], B1[T][c], acc, 0, 0, 0);
                D[mh][T] = acc;
            }
        }
        #pragma unroll
        for (int mh = 0; mh < 2; ++mh) {
            #pragma unroll
            for (int r = 0; r < 4; ++r) {
                const float i1 = sig_f(D[mh][0][r]);
                const float f1 = sig_f(D[mh][1][r]);
                const float g1 = tanh_f(D[mh][2][r]);
                const float o1 = sig_f(D[mh][3][r]);
                const float c1 = f1 * c1s[mh][r] + i1 * g1;
                h1v[mh][r] = o1 * tanh_f(c1);
            }
        }
    }

    // ---- classifier ----
    if (lm < 10) {
        #pragma unroll
        for (int mh = 0; mh < 2; ++mh)
            #pragma unroll
            for (int r = 0; r < 4; ++r)
                hfinw[(16 * mh + 4 * q + r) * 12 + lm] = h1v[mh][r];
    }
    FENCE();
    if (lm < 10) {
        float wc[10];
        #pragma unroll
        for (int j = 0; j < 10; ++j) wc[j] = w_cls[lm * 10 + j];
        const float bo = b_cls[lm];
        #pragma unroll
        for (int mh = 0; mh < 2; ++mh) {
            #pragma unroll
            for (int r = 0; r < 4; ++r) {
                const int m = 16 * mh + 4 * q + r;
                float acc = bo;
                #pragma unroll
                for (int j = 0; j < 10; ++j) acc += hfinw[m * 12 + j] * wc[j];
                out[(size_t)(sbase + m) * 10 + lm] = acc;
            }
        }
    }
}

extern "C" void kernel_launch(void* const* d_in, const int* in_sizes, int n_in,
                              void* d_out, int out_size, void* d_ws, size_t ws_size,
                              hipStream_t stream) {
    const float* x     = (const float*)d_in[0];
    const float* w_ih0 = (const float*)d_in[1];
    const float* w_hh0 = (const float*)d_in[2];
    const float* b_ih0 = (const float*)d_in[3];
    const float* b_hh0 = (const float*)d_in[4];
    const float* w_ih1 = (const float*)d_in[5];
    const float* w_hh1 = (const float*)d_in[6];
    const float* b_ih1 = (const float*)d_in[7];
    const float* b_hh1 = (const float*)d_in[8];
    const float* w_cls = (const float*)d_in[9];
    const float* b_cls = (const float*)d_in[10];
    float* out = (float*)d_out;

    const int B = in_sizes[0] / (TSTEPS * DDIM);   // 32768
    const int grid = B / 64;                       // 512 blocks x 2 waves x 32 samples

    hipLaunchKernelGGL(lstm2_mfma_kernel, dim3(grid), dim3(128), 0, stream,
                       x, w_ih0, w_hh0, b_ih0, b_hh0,
                       w_ih1, w_hh1, b_ih1, b_hh1,
                       w_cls, b_cls, out);
}